// Round 4
// baseline (694.836 us; speedup 1.0000x reference)
//
#include <hip/hip_runtime.h>
#include <hip/hip_bf16.h>
#include <math.h>

// Problem constants
#define B_  128
#define C_  256
#define J_  5
#define BS_ 5
#define P_  441          // 21*21
#define N_  2205         // BS_*P_
#define REG_ 1e-6f

typedef __attribute__((ext_vector_type(8))) short short8_t;   // 8 bf16 (4 VGPR)
typedef __attribute__((ext_vector_type(4))) float f32x4;

__device__ __forceinline__ unsigned short f2bf(float f) {     // RNE f32->bf16
    union { float f; unsigned int u; } x; x.f = f;
    unsigned int r = (x.u + 0x7FFFu + ((x.u >> 16) & 1u)) >> 16;
    return (unsigned short)r;
}
__device__ __forceinline__ float bf2f(unsigned short u) {
    union { unsigned int u; float f; } x; x.u = ((unsigned int)u) << 16;
    return x.f;
}

// ---------------------------------------------------------------------------
// Kernel 1: per-class channel means over x2.
// ---------------------------------------------------------------------------
__global__ __launch_bounds__(256) void mean_kernel(const float* __restrict__ x2,
                                                   float* __restrict__ mean) {
    const int w    = threadIdx.x >> 6;
    const int lane = threadIdx.x & 63;
    const int j    = blockIdx.x >> 6;
    const int c    = (blockIdx.x & 63) * 4 + w;
    float s = 0.f;
    for (int bs = 0; bs < BS_; ++bs) {
        const float* base = x2 + (size_t)((j * BS_ + bs) * C_ + c) * P_;
        #pragma unroll
        for (int k = 0; k < 7; ++k) {
            int p = k * 64 + lane;
            if (p < P_) s += base[p];
        }
    }
    #pragma unroll
    for (int off = 32; off; off >>= 1) s += __shfl_down(s, off);
    if (lane == 0) mean[j * C_ + c] = s * (1.f / (float)N_);
}

// ---------------------------------------------------------------------------
// Kernel 2: per-(b,c) scale = 1/||q||_2 and mu = mean(q*scale) over P.
// ---------------------------------------------------------------------------
__global__ __launch_bounds__(256) void qstats_kernel(const float* __restrict__ x1,
                                                     float* __restrict__ scale,
                                                     float* __restrict__ mu) {
    const int w    = threadIdx.x >> 6;
    const int lane = threadIdx.x & 63;
    const int row  = blockIdx.x * 4 + w;
    const float* base = x1 + (size_t)row * P_;
    float s1 = 0.f, s2 = 0.f;
    #pragma unroll
    for (int k = 0; k < 7; ++k) {
        int p = k * 64 + lane;
        if (p < P_) { float v = base[p]; s1 += v; s2 += v * v; }
    }
    #pragma unroll
    for (int off = 32; off; off >>= 1) {
        s1 += __shfl_down(s1, off);
        s2 += __shfl_down(s2, off);
    }
    if (lane == 0) {
        float sc = 1.f / sqrtf(s2);
        scale[row] = sc;
        mu[row]    = s1 * sc * (1.f / (float)P_);
    }
}

// ---------------------------------------------------------------------------
// Kernel 3: raw second-moment covraw[j][c][d] = sum_n X[j,n,c]*X[j,n,d]
// ---------------------------------------------------------------------------
__global__ __launch_bounds__(256) void cov_kernel(const float* __restrict__ x2,
                                                  float* __restrict__ covraw) {
    __shared__ float As[64][33];
    __shared__ float Bs2[64][33];
    const int tid  = threadIdx.x;
    const int tile = blockIdx.x;
    const int j    = blockIdx.y;
    const int bs   = blockIdx.z;
    const int c0   = (tile >> 2) * 64;
    const int d0   = (tile & 3) * 64;
    const float* basec = x2 + (size_t)((j * BS_ + bs) * C_ + c0) * P_;
    const float* based = x2 + (size_t)((j * BS_ + bs) * C_ + d0) * P_;
    const int tcx = tid & 15;
    const int trx = tid >> 4;
    float acc[4][4] = {};
    for (int p0 = 0; p0 < P_; p0 += 32) {
        #pragma unroll
        for (int k = 0; k < 8; ++k) {
            int idx = k * 256 + tid;
            int ci = idx >> 5, ni = idx & 31;
            int p = p0 + ni;
            As[ci][ni]  = (p < P_) ? basec[ci * P_ + p] : 0.f;
            Bs2[ci][ni] = (p < P_) ? based[ci * P_ + p] : 0.f;
        }
        __syncthreads();
        #pragma unroll
        for (int ni = 0; ni < 32; ++ni) {
            float a[4], bb[4];
            #pragma unroll
            for (int i = 0; i < 4; ++i) a[i]  = As[trx * 4 + i][ni];
            #pragma unroll
            for (int i = 0; i < 4; ++i) bb[i] = Bs2[tcx * 4 + i][ni];
            #pragma unroll
            for (int i = 0; i < 4; ++i)
                #pragma unroll
                for (int jj = 0; jj < 4; ++jj)
                    acc[i][jj] += a[i] * bb[jj];
        }
        __syncthreads();
    }
    #pragma unroll
    for (int i = 0; i < 4; ++i)
        #pragma unroll
        for (int jj = 0; jj < 4; ++jj)
            atomicAdd(&covraw[(size_t)j * C_ * C_ + (size_t)(c0 + trx * 4 + i) * C_ +
                              (d0 + tcx * 4 + jj)], acc[i][jj]);
}

// ---------------------------------------------------------------------------
// Kernel 4: BLOCKED register-resident Gauss-Jordan, 512 threads.
// Thread t owns rows 8*rg..8*rg+7 (rg=t>>4), cols 16*cg..16*cg+15 (cg=t&15):
// own[8][16] = 128 VGPR. Wave w owns rows 32w..32w+31; panel s (rows
// 16s..16s+15) lives in wave s>>1. Per step:
//  1. panel threads publish rows to LDS slab PL; cg==s threads publish B-hat.
//  2. wave s>>1 eliminates the 16x256 panel in LDS (intra-wave), panel
//     threads read back, +I written at panel diagonal.
//  3. non-panel threads: own[u][c] -= sum_i Bb[row u][i] * PL[i][c].
// DS traffic per thread per step: 64 PL + 32 Bhat reads (vs 256 in the
// row-sliced variant) -> VALU-bound, not LDS-bound.
// ---------------------------------------------------------------------------
__global__ __launch_bounds__(512) void invert_kernel(const float* __restrict__ covraw,
                                                     const float* __restrict__ mean,
                                                     unsigned short* __restrict__ invb) {
    const int j    = blockIdx.x;
    const int t    = threadIdx.x;
    const int rg   = t >> 4;         // 0..31 -> rows 8rg..8rg+7
    const int cg   = t & 15;         // cols 16cg..16cg+15
    const int w    = t >> 6;         // 0..7
    const int lane = t & 63;
    const int slabc = (cg >> 2) * 68 + (cg & 3) * 16;  // LDS col offset of this thread's 16 cols

    __shared__ float PL[16 * 272];   // panel rows: rr*272 + (c>>6)*68 + (c&63)
    __shared__ float Bb[256 * 20];   // B-hat: row r, 16 coeffs (pad to 20)
    __shared__ float mj[256];

    if (t < 256) mj[t] = mean[j * C_ + t];
    __syncthreads();

    float own[8][16];
    {
        const float invNm1 = 1.f / (float)(N_ - 1);
        #pragma unroll
        for (int u = 0; u < 8; ++u) {
            const int r = 8 * rg + u;
            const float* Rr = covraw + (size_t)j * 65536 + (size_t)r * 256 + cg * 16;
            const float murN = mj[r] * (float)N_;
            #pragma unroll
            for (int i4 = 0; i4 < 4; ++i4) {
                float4 rv = *(const float4*)&Rr[i4 * 4];
                float4 mv = *(const float4*)&mj[cg * 16 + i4 * 4];
                float v0 = (rv.x - murN * mv.x) * invNm1;
                float v1 = (rv.y - murN * mv.y) * invNm1;
                float v2 = (rv.z - murN * mv.z) * invNm1;
                float v3 = (rv.w - murN * mv.w) * invNm1;
                if (cg * 16 + i4 * 4 + 0 == r) v0 += REG_;
                if (cg * 16 + i4 * 4 + 1 == r) v1 += REG_;
                if (cg * 16 + i4 * 4 + 2 == r) v2 += REG_;
                if (cg * 16 + i4 * 4 + 3 == r) v3 += REG_;
                own[u][i4 * 4 + 0] = v0; own[u][i4 * 4 + 1] = v1;
                own[u][i4 * 4 + 2] = v2; own[u][i4 * 4 + 3] = v3;
            }
        }
    }

    for (int s = 0; s < 16; ++s) {
        const int p0 = s * 16;
        const int qp = p0 >> 6;
        const int co = p0 & 63;
        const bool inPanel = ((rg >> 1) == s);

        // ---- 1. publish ----
        if (inPanel) {
            const int rbase = (rg & 1) * 8;
            #pragma unroll
            for (int u = 0; u < 8; ++u)
                #pragma unroll
                for (int i4 = 0; i4 < 4; ++i4)
                    *(float4*)&PL[(rbase + u) * 272 + slabc + i4 * 4] =
                        make_float4(own[u][i4 * 4], own[u][i4 * 4 + 1],
                                    own[u][i4 * 4 + 2], own[u][i4 * 4 + 3]);
        }
        if (cg == s) {
            #pragma unroll
            for (int u = 0; u < 8; ++u)
                #pragma unroll
                for (int i4 = 0; i4 < 4; ++i4)
                    *(float4*)&Bb[(8 * rg + u) * 20 + i4 * 4] =
                        make_float4(own[u][i4 * 4], own[u][i4 * 4 + 1],
                                    own[u][i4 * 4 + 2], own[u][i4 * 4 + 3]);
        }
        __syncthreads();

        // ---- 2. panel elimination (wave s>>1, intra-wave) ----
        if (w == (s >> 1)) {
            const int coff = (lane >> 4) * 68 + (lane & 15) * 4;  // lane's 4-col chunk (cols 4*lane..+3)
            #pragma unroll
            for (int i = 0; i < 16; ++i) {
                const int pvoff = qp * 68 + co + i;
                const bool haspiv = (lane == ((p0 + i) >> 2));
                float pv = PL[i * 272 + pvoff];
                float d  = 1.f / pv;
                float4 pr = *(const float4*)&PL[i * 272 + coff];
                pr.x *= d; pr.y *= d; pr.z *= d; pr.w *= d;
                if (haspiv) ((float*)&pr)[i & 3] = d;
                *(float4*)&PL[i * 272 + coff] = pr;
                #pragma unroll
                for (int rb = 0; rb < 4; ++rb) {
                    float  g[4];
                    float4 v[4];
                    #pragma unroll
                    for (int u = 0; u < 4; ++u) {
                        int rr = rb * 4 + u;
                        g[u] = PL[rr * 272 + pvoff];
                        v[u] = *(const float4*)&PL[rr * 272 + coff];
                    }
                    #pragma unroll
                    for (int u = 0; u < 4; ++u) {
                        int rr = rb * 4 + u;
                        if (rr == i) continue;
                        float4 nv;
                        nv.x = fmaf(-g[u], pr.x, v[u].x);
                        nv.y = fmaf(-g[u], pr.y, v[u].y);
                        nv.z = fmaf(-g[u], pr.z, v[u].z);
                        nv.w = fmaf(-g[u], pr.w, v[u].w);
                        if (haspiv) ((float*)&nv)[i & 3] = -g[u] * d;
                        *(float4*)&PL[rr * 272 + coff] = nv;
                    }
                }
            }
            // readback (panel threads of this wave)
            if (inPanel) {
                const int rbase = (rg & 1) * 8;
                #pragma unroll
                for (int u = 0; u < 8; ++u)
                    #pragma unroll
                    for (int i4 = 0; i4 < 4; ++i4) {
                        float4 v = *(const float4*)&PL[(rbase + u) * 272 + slabc + i4 * 4];
                        own[u][i4 * 4 + 0] = v.x; own[u][i4 * 4 + 1] = v.y;
                        own[u][i4 * 4 + 2] = v.z; own[u][i4 * 4 + 3] = v.w;
                    }
            }
            // +I at panel diagonal (after readback; enables trailing FMA trick)
            if (lane < 16) PL[lane * 272 + qp * 68 + co + lane] += 1.f;
        }
        __syncthreads();

        // ---- 3. trailing rank-16 update ----
        if (!inPanel) {
            #pragma unroll
            for (int i4 = 0; i4 < 4; ++i4) {
                float4 bh[8];
                #pragma unroll
                for (int u = 0; u < 8; ++u)
                    bh[u] = *(const float4*)&Bb[(8 * rg + u) * 20 + i4 * 4];
                #pragma unroll
                for (int ii = 0; ii < 4; ++ii) {
                    const int i = i4 * 4 + ii;
                    float4 pl0 = *(const float4*)&PL[i * 272 + slabc + 0];
                    float4 pl1 = *(const float4*)&PL[i * 272 + slabc + 4];
                    float4 pl2 = *(const float4*)&PL[i * 272 + slabc + 8];
                    float4 pl3 = *(const float4*)&PL[i * 272 + slabc + 12];
                    #pragma unroll
                    for (int u = 0; u < 8; ++u) {
                        const float g = ((const float*)&bh[u])[ii];
                        own[u][0]  = fmaf(-g, pl0.x, own[u][0]);
                        own[u][1]  = fmaf(-g, pl0.y, own[u][1]);
                        own[u][2]  = fmaf(-g, pl0.z, own[u][2]);
                        own[u][3]  = fmaf(-g, pl0.w, own[u][3]);
                        own[u][4]  = fmaf(-g, pl1.x, own[u][4]);
                        own[u][5]  = fmaf(-g, pl1.y, own[u][5]);
                        own[u][6]  = fmaf(-g, pl1.z, own[u][6]);
                        own[u][7]  = fmaf(-g, pl1.w, own[u][7]);
                        own[u][8]  = fmaf(-g, pl2.x, own[u][8]);
                        own[u][9]  = fmaf(-g, pl2.y, own[u][9]);
                        own[u][10] = fmaf(-g, pl2.z, own[u][10]);
                        own[u][11] = fmaf(-g, pl2.w, own[u][11]);
                        own[u][12] = fmaf(-g, pl3.x, own[u][12]);
                        own[u][13] = fmaf(-g, pl3.y, own[u][13]);
                        own[u][14] = fmaf(-g, pl3.z, own[u][14]);
                        own[u][15] = fmaf(-g, pl3.w, own[u][15]);
                    }
                }
            }
        }
        __syncthreads();
    }

    // epilogue: bf16 store (rows 8rg..8rg+7, cols 16cg..+15)
    #pragma unroll
    for (int u = 0; u < 8; ++u) {
        unsigned short* dst = invb + (size_t)j * 65536 + (size_t)(8 * rg + u) * 256 + cg * 16;
        #pragma unroll
        for (int h = 0; h < 2; ++h) {
            ushort4 o0, o1;
            o0.x = f2bf(own[u][h * 8 + 0]); o0.y = f2bf(own[u][h * 8 + 1]);
            o0.z = f2bf(own[u][h * 8 + 2]); o0.w = f2bf(own[u][h * 8 + 3]);
            o1.x = f2bf(own[u][h * 8 + 4]); o1.y = f2bf(own[u][h * 8 + 5]);
            o1.z = f2bf(own[u][h * 8 + 6]); o1.w = f2bf(own[u][h * 8 + 7]);
            *(ushort4*)&dst[h * 8 + 0] = o0;
            *(ushort4*)&dst[h * 8 + 4] = o1;
        }
    }
}

// ---------------------------------------------------------------------------
// Kernel 5: MFMA einsum (unchanged from round 3).
// ---------------------------------------------------------------------------
__global__ __launch_bounds__(256) void einsum_kernel(const float* __restrict__ x1,
                                                     const unsigned short* __restrict__ invb,
                                                     const float* __restrict__ scale,
                                                     const float* __restrict__ mu,
                                                     float* __restrict__ out) {
    __shared__ unsigned short dT[112 * 256];   // byte addr = p*512 + c*2, ^((p&7)<<4)
    __shared__ float simbuf[4][7][16];
    char* dTc = (char*)dT;

    const int pt = blockIdx.x;                 // 0..3
    const int b  = blockIdx.y;                 // 0..127
    const int t  = threadIdx.x;
    const int p0 = pt * 112;
    const int w    = t >> 6;
    const int lane = t & 63;

    // ---- stage diffT ----
    {
        const int g32 = t >> 5;                // 0..7
        const int l32 = t & 31;
        for (int cc = 0; cc < 32; ++cc) {
            const int c = g32 * 32 + cc;
            const float sc = scale[b * C_ + c];
            const float m  = mu[b * C_ + c];
            const float* xr = x1 + (size_t)(b * C_ + c) * P_ + p0;
            #pragma unroll
            for (int mm = 0; mm < 4; ++mm) {
                int p = mm * 32 + l32;
                if (p < 112) {
                    float v = 0.f;
                    if (p0 + p < P_) v = xr[p] * sc - m;
                    int byte = (p * 512 + c * 2) ^ ((p & 7) << 4);
                    *(unsigned short*)(dTc + byte) = f2bf(v);
                }
            }
        }
    }
    __syncthreads();

    for (int j = 0; j < J_; ++j) {
        const unsigned short* invj = invb + (size_t)j * 65536;
        f32x4 acc[4][7];
        #pragma unroll
        for (int mt = 0; mt < 4; ++mt)
            #pragma unroll
            for (int nt = 0; nt < 7; ++nt)
                acc[mt][nt] = (f32x4){0.f, 0.f, 0.f, 0.f};

        for (int kt = 0; kt < 8; ++kt) {
            const int k = kt * 32 + (lane >> 4) * 8;
            short8_t a[4], bb[7];
            #pragma unroll
            for (int mt = 0; mt < 4; ++mt) {
                int m = w * 64 + mt * 16 + (lane & 15);
                a[mt] = *(const short8_t*)(invj + (size_t)m * 256 + k);
            }
            #pragma unroll
            for (int nt = 0; nt < 7; ++nt) {
                int n = nt * 16 + (lane & 15);
                int byte = (n * 512 + k * 2) ^ ((n & 7) << 4);
                bb[nt] = *(const short8_t*)(dTc + byte);
            }
            #pragma unroll
            for (int mt = 0; mt < 4; ++mt)
                #pragma unroll
                for (int nt = 0; nt < 7; ++nt)
                    acc[mt][nt] = __builtin_amdgcn_mfma_f32_16x16x32_bf16(
                        a[mt], bb[nt], acc[mt][nt], 0, 0, 0);
        }

        // ---- dot with diff + reduce ----
        float sim[7];
        #pragma unroll
        for (int nt = 0; nt < 7; ++nt) sim[nt] = 0.f;
        #pragma unroll
        for (int mt = 0; mt < 4; ++mt) {
            const int m = w * 64 + mt * 16 + (lane >> 4) * 4;
            #pragma unroll
            for (int nt = 0; nt < 7; ++nt) {
                const int n = nt * 16 + (lane & 15);
                int byte = (n * 512 + m * 2) ^ ((n & 7) << 4);
                ushort4 du = *(const ushort4*)(dTc + byte);
                sim[nt] += bf2f(du.x) * acc[mt][nt][0];
                sim[nt] += bf2f(du.y) * acc[mt][nt][1];
                sim[nt] += bf2f(du.z) * acc[mt][nt][2];
                sim[nt] += bf2f(du.w) * acc[mt][nt][3];
            }
        }
        #pragma unroll
        for (int nt = 0; nt < 7; ++nt) {
            float v = sim[nt];
            v += __shfl_xor(v, 16);
            v += __shfl_xor(v, 32);
            if (lane < 16) simbuf[w][nt][lane] = v;
        }
        __syncthreads();
        if (t < 112) {
            const int nt = t >> 4;
            float s = simbuf[0][nt][t & 15] + simbuf[1][nt][t & 15] +
                      simbuf[2][nt][t & 15] + simbuf[3][nt][t & 15];
            int p = p0 + t;
            if (p < P_) out[(size_t)b * (J_ * P_) + j * P_ + p] = s;
        }
        __syncthreads();
    }
}

// ---------------------------------------------------------------------------
extern "C" void kernel_launch(void* const* d_in, const int* in_sizes, int n_in,
                              void* d_out, int out_size, void* d_ws, size_t ws_size,
                              hipStream_t stream) {
    const float* x1 = (const float*)d_in[0];   // [128,256,21,21]
    const float* x2 = (const float*)d_in[1];   // [5,5,256,21,21]
    float* out = (float*)d_out;                // [128, 5*441]
    float* ws  = (float*)d_ws;

    float* mean   = ws;                                   // 1280
    float* scale  = mean + J_ * C_;                       // 32768
    float* mu     = scale + B_ * C_;                      // 32768
    float* covraw = mu + B_ * C_;                         // 327680
    unsigned short* invb = (unsigned short*)(covraw + (size_t)J_ * C_ * C_);  // 327680 bf16

    hipMemsetAsync(covraw, 0, (size_t)J_ * C_ * C_ * sizeof(float), stream);

    mean_kernel  <<<J_ * 64, 256, 0, stream>>>(x2, mean);
    qstats_kernel<<<(B_ * C_) / 4, 256, 0, stream>>>(x1, scale, mu);
    cov_kernel   <<<dim3(16, J_, BS_), 256, 0, stream>>>(x2, covraw);
    invert_kernel<<<J_, 512, 0, stream>>>(covraw, mean, invb);
    einsum_kernel<<<dim3(4, B_), 256, 0, stream>>>(x1, invb, scale, mu, out);
}